// Round 7
// baseline (168.275 us; speedup 1.0000x reference)
//
#include <hip/hip_runtime.h>
#include <math.h>

// ---------------------------------------------------------------------------
// AttentionBlock: GN(4,256) -> QKV 1x1 conv -> 2-head attn (N=1024, hd=128)
// -> proj -> +residual.  B=16, C=256, H=W=32 (N=1024), fp32 in/out.
// R7: attn rebuilt on 32x32x16 MFMA (2x FLOP per LDS byte): wave owns
// 32 q-rows x 32-of-64 j (split-j, 8 waves/CU), xor32 packed P re-frag,
// end-of-kernel j-half merge. Keeps R6 prefetch dbuf + XCD swizzle.
// prep/qkv_fused/proj_gemm unchanged from R6.
// ---------------------------------------------------------------------------

typedef __attribute__((ext_vector_type(8))) short bf16x8;    // 8 bf16 = 4 VGPRs
typedef __attribute__((ext_vector_type(4))) float f32x4;
typedef __attribute__((ext_vector_type(16))) float f32x16;

__device__ __forceinline__ unsigned short f2bf(float f) {   // RNE-ish
    union { float f; unsigned u; } v; v.f = f;
    return (unsigned short)((v.u + 0x7FFFu + ((v.u >> 16) & 1u)) >> 16);
}
__device__ __forceinline__ unsigned bfbits(float f) {       // +half (round up)
    union { float f; unsigned u; } v; v.f = f;
    return v.u + 0x8000u;
}
// pack two floats -> (bf(a) | bf(b)<<16) in 3 VALU ops
__device__ __forceinline__ unsigned packbf(float a, float b) {
    return __builtin_amdgcn_perm(bfbits(b), bfbits(a), 0x07060302u);
}

__device__ __forceinline__ void gload_lds16(const void* g, void* l) {
    __builtin_amdgcn_global_load_lds(
        (const __attribute__((address_space(1))) unsigned int*)g,
        (__attribute__((address_space(3))) unsigned int*)l, 16, 0, 0);
}

// ------------------------------------------- prep: weights->bf16 + GN stats
__global__ __launch_bounds__(256) void prep(const float* __restrict__ wq,
                                            const float* __restrict__ wk,
                                            const float* __restrict__ wv,
                                            const float* __restrict__ wp,
                                            unsigned short* __restrict__ oq,
                                            unsigned short* __restrict__ ok,
                                            unsigned short* __restrict__ ov,
                                            unsigned short* __restrict__ op,
                                            const float* __restrict__ x,
                                            float* __restrict__ acc) {
    int bid = blockIdx.x;
    if (bid < 256) {
        int idx = bid * 1024 + threadIdx.x * 4;
        int which = idx >> 16, i = idx & 65535;
        const float* src = (which == 0) ? wq : (which == 1) ? wk : (which == 2) ? wv : wp;
        unsigned short* dst = (which == 0) ? oq : (which == 1) ? ok : (which == 2) ? ov : op;
        // fold softmax scale 512^-0.5 AND log2(e) into wq (softmax uses exp2)
        float scl = (which == 0) ? (0.044194173824159216f * 1.4426950408889634f) : 1.0f;
        float4 v = *(const float4*)(src + i);
        ushort4 o;
        o.x = f2bf(v.x * scl); o.y = f2bf(v.y * scl);
        o.z = f2bf(v.z * scl); o.w = f2bf(v.w * scl);
        *(ushort4*)(dst + i) = o;
    } else {
        int bid2 = bid - 256;                  // [0,512)
        int bg = bid2 >> 3, ch = bid2 & 7;
        const float4* xp = (const float4*)(x + (size_t)bg * 65536 + ch * 8192);
        float s = 0.f, s2 = 0.f;
#pragma unroll
        for (int i = 0; i < 8; i++) {
            float4 v = xp[threadIdx.x + i * 256];
            s  += v.x + v.y + v.z + v.w;
            s2 += v.x * v.x + v.y * v.y + v.z * v.z + v.w * v.w;
        }
        for (int m = 1; m < 64; m <<= 1) { s += __shfl_xor(s, m); s2 += __shfl_xor(s2, m); }
        __shared__ float ls[8];
        int w = threadIdx.x >> 6, lane = threadIdx.x & 63;
        if (lane == 0) { ls[w] = s; ls[4 + w] = s2; }
        __syncthreads();
        if (threadIdx.x == 0) {
            acc[bg * 16 + ch * 2]     = ls[0] + ls[1] + ls[2] + ls[3];
            acc[bg * 16 + ch * 2 + 1] = ls[4] + ls[5] + ls[6] + ls[7];
        }
    }
}

// --------------------------------------------------- QKV GEMM fused with GN
__global__ __launch_bounds__(256) void qkv_fused(const float* __restrict__ x,
                                                 const float* __restrict__ acc,
                                                 const float* __restrict__ gnw,
                                                 const float* __restrict__ gnb,
                                                 const unsigned short* __restrict__ wqb,
                                                 const unsigned short* __restrict__ wkb,
                                                 const unsigned short* __restrict__ wvb,
                                                 unsigned short* __restrict__ qt,
                                                 unsigned short* __restrict__ kt,
                                                 unsigned short* __restrict__ vv) {
    int b = blockIdx.z, half = blockIdx.y, nx = blockIdx.x;
    int n0 = nx * 64;
    int t = threadIdx.x, w = t >> 6, lane = t & 63, quad = lane >> 4, c4 = lane & 15;
    __shared__ __align__(16) unsigned short xl[17408];   // p1: [64][264]; p2: Q-et@0, K-et@8704
    __shared__ __align__(16) unsigned short ebuf[9216];  // V-et2 [128][72]
    __shared__ float gs[8];
    if (t < 4) {
        float s0 = 0.f, s1 = 0.f;
#pragma unroll
        for (int p = 0; p < 8; p++) {
            s0 += acc[(b * 4 + t) * 16 + p * 2];
            s1 += acc[(b * 4 + t) * 16 + p * 2 + 1];
        }
        float mean = s0 * (1.f / 65536.f);
        float var = s1 * (1.f / 65536.f) - mean * mean;
        gs[2 * t] = mean;
        gs[2 * t + 1] = rsqrtf(var + 1e-5f);
    }
    __syncthreads();
    {
        int col = t & 15, crow = t >> 4;
#pragma unroll
        for (int p = 0; p < 16; p++) {
            int c = p * 16 + crow;
            int g = c >> 6;
            float sc = gs[g * 2 + 1] * gnw[c];
            float bs = gnb[c] - gs[g * 2] * sc;
            float4 v = *(const float4*)(x + ((size_t)b * 256 + c) * 1024 + n0 + col * 4);
            int nl = col * 4;
            xl[(nl + 0) * 264 + c] = (unsigned short)(bfbits(fmaf(v.x, sc, bs)) >> 16);
            xl[(nl + 1) * 264 + c] = (unsigned short)(bfbits(fmaf(v.y, sc, bs)) >> 16);
            xl[(nl + 2) * 264 + c] = (unsigned short)(bfbits(fmaf(v.z, sc, bs)) >> 16);
            xl[(nl + 3) * 264 + c] = (unsigned short)(bfbits(fmaf(v.w, sc, bs)) >> 16);
        }
    }
    __syncthreads();
    int wm = (w >> 1) * 64, wn = (w & 1) * 32;
    int mbase = half * 128 + wm;
    int bh = b * 2 + half;
    f32x4 aq[4][2] = {}, akk[4][2] = {}, av[4][2] = {};
#pragma unroll
    for (int k = 0; k < 256; k += 32) {
        bf16x8 bfr[2];
#pragma unroll
        for (int i = 0; i < 2; i++)
            bfr[i] = *(const bf16x8*)&xl[(wn + i * 16 + c4) * 264 + k + quad * 8];
#pragma unroll
        for (int mi = 0; mi < 4; mi++) {
            bf16x8 afq = *(const bf16x8*)(wqb + (mbase + mi * 16 + c4) * 256 + k + quad * 8);
            bf16x8 afk = *(const bf16x8*)(wkb + (mbase + mi * 16 + c4) * 256 + k + quad * 8);
            bf16x8 afv = *(const bf16x8*)(wvb + (mbase + mi * 16 + c4) * 256 + k + quad * 8);
#pragma unroll
            for (int ni = 0; ni < 2; ni++) {
                aq[mi][ni]  = __builtin_amdgcn_mfma_f32_16x16x32_bf16(afq, bfr[ni], aq[mi][ni], 0, 0, 0);
                akk[mi][ni] = __builtin_amdgcn_mfma_f32_16x16x32_bf16(afk, bfr[ni], akk[mi][ni], 0, 0, 0);
                av[mi][ni]  = __builtin_amdgcn_mfma_f32_16x16x32_bf16(afv, bfr[ni], av[mi][ni], 0, 0, 0);
            }
        }
    }
    __syncthreads();
#pragma unroll
    for (int mi = 0; mi < 4; mi++)
#pragma unroll
        for (int ni = 0; ni < 2; ni++) {
            int row = wn + ni * 16 + c4;          // i-local
            int col = wm + mi * 16 + quad * 4;    // ch
            uint2 uq, uk;
            uq.x = packbf(aq[mi][ni][0], aq[mi][ni][1]);
            uq.y = packbf(aq[mi][ni][2], aq[mi][ni][3]);
            uk.x = packbf(akk[mi][ni][0], akk[mi][ni][1]);
            uk.y = packbf(akk[mi][ni][2], akk[mi][ni][3]);
            *(uint2*)&xl[row * 136 + col] = uq;
            *(uint2*)&xl[8704 + row * 136 + col] = uk;
#pragma unroll
            for (int r = 0; r < 4; r++)
                ebuf[(col + r) * 72 + row] = f2bf(av[mi][ni][r]);
        }
    __syncthreads();
#pragma unroll
    for (int p = 0; p < 4; p++) {
        int i = p * 16 + (t >> 4), off = (t & 15) * 8;
        *(bf16x8*)(qt + ((size_t)bh * 1024 + n0 + i) * 128 + off) =
            *(const bf16x8*)&xl[i * 136 + off];
        *(bf16x8*)(kt + ((size_t)bh * 1024 + n0 + i) * 128 + off) =
            *(const bf16x8*)&xl[8704 + i * 136 + off];
    }
#pragma unroll
    for (int p = 0; p < 4; p++) {
        int ch = p * 32 + (t >> 3), off = (t & 7) * 8;
        *(bf16x8*)(vv + ((size_t)bh * 128 + ch) * 1024 + n0 + off) =
            *(const bf16x8*)&ebuf[ch * 72 + off];
    }
}

// ------------------------------------------------------- flash attention v7
// 32x32x16 MFMA. 1D grid 512 XCD-swizzled, 4 waves: wave (qh=w&1, jh=w>>1)
// owns 32 q-rows x 32-of-64 j per tile. Double-buffered K/V staging, one
// barrier per jt. No online max. P re-frag = xor32 packed exchange.
// Layouts (32x32x16): A[m=lane&31][k=8*(lane>>5)+e]; B[k][n=lane&31] same k;
// D: col=lane&31, row=(reg&3)+8*(reg>>2)+4*(lane>>5).
__global__ __launch_bounds__(256) void attn_kernel(const unsigned short* __restrict__ qt,
                                                   const unsigned short* __restrict__ kt,
                                                   const unsigned short* __restrict__ vv,
                                                   unsigned short* __restrict__ ot) {
    int L = blockIdx.x;
    int xcd = L & 7, jj = L >> 3;
    int bh = (jj >> 4) * 8 + xcd;       // 4 bh per XCD
    int qb = jj & 15;
    int b = bh >> 1, h = bh & 1;
    int tid = threadIdx.x, w = tid >> 6, lane = tid & 63;
    int l31 = lane & 31, hbp = lane >> 5;
    int qh = w & 1, jh = w >> 1;
    __shared__ __align__(16) unsigned short klds[2][8192];   // 2 x 16 KB K-tile
    __shared__ __align__(16) unsigned short vlds[2][8192];   // 2 x 16 KB V-tile

    const unsigned short* qp = qt + (size_t)bh * 1024 * 128;
    const unsigned short* kp = kt + (size_t)bh * 1024 * 128;
    const unsigned short* vp = vv + (size_t)bh * 128 * 1024;
    int i0 = qb * 64 + qh * 32;

    // Q B-frags: Q[i0 + l31][ks*16 + hbp*8 + e], 8 k-steps kept in regs
    bf16x8 bq[8];
#pragma unroll
    for (int ks = 0; ks < 8; ks++)
        bq[ks] = *(const bf16x8*)(qp + (size_t)(i0 + l31) * 128 + ks * 16 + hbp * 8);

    float lsum = 0.f;          // partial row-sum for i = i0 + l31
    f32x16 oacc[4] = {};       // O[i-local = rowmap(reg,hbp)][c = cs*32 + l31]

    // ---- prefetch tile 0 into buffer 0 (32 chunks of 1KB, 8 per wave)
#pragma unroll
    for (int t = 0; t < 8; t++) {
        int chunk = w * 8 + t;
        if (chunk < 16) {        // K chunk (js, ks): js=chunk>>3, ks=chunk&7
            int js = chunk >> 3, ks = chunk & 7;
            gload_lds16(kp + (size_t)(js * 32 + l31) * 128 + ks * 16 + hbp * 8,
                        &klds[0][chunk * 512]);
        } else {                 // V chunk (cs, jseg): cc = cs*4 + jseg
            int cc = chunk - 16, cs = cc >> 2, jseg = cc & 3;
            gload_lds16(vp + (size_t)(cs * 32 + l31) * 1024 + jseg * 16 + hbp * 8,
                        &vlds[0][cc * 512]);
        }
    }

    for (int jt = 0; jt < 16; jt++) {
        int cur = jt & 1;
        __syncthreads();   // staging of cur visible; next-buf reads done
        if (jt < 15) {
            int j0n = (jt + 1) * 64, nb = cur ^ 1;
#pragma unroll
            for (int t = 0; t < 8; t++) {
                int chunk = w * 8 + t;
                if (chunk < 16) {
                    int js = chunk >> 3, ks = chunk & 7;
                    gload_lds16(kp + (size_t)(j0n + js * 32 + l31) * 128 + ks * 16 + hbp * 8,
                                &klds[nb][chunk * 512]);
                } else {
                    int cc = chunk - 16, cs = cc >> 2, jseg = cc & 3;
                    gload_lds16(vp + (size_t)(cs * 32 + l31) * 1024 + j0n + jseg * 16 + hbp * 8,
                                &vlds[nb][cc * 512]);
                }
            }
        }

        // ---- S^T 32x32 tile for this wave's j-half (2 acc chains for ILP)
        f32x16 st0 = {}, st1 = {};
#pragma unroll
        for (int ks = 0; ks < 8; ks += 2) {
            bf16x8 ak0 = *(const bf16x8*)&klds[cur][(jh * 8 + ks) * 512 + lane * 8];
            bf16x8 ak1 = *(const bf16x8*)&klds[cur][(jh * 8 + ks + 1) * 512 + lane * 8];
            st0 = __builtin_amdgcn_mfma_f32_32x32x16_bf16(ak0, bq[ks], st0, 0, 0, 0);
            st1 = __builtin_amdgcn_mfma_f32_32x32x16_bf16(ak1, bq[ks + 1], st1, 0, 0, 0);
        }

        // ---- p = exp2(s); accumulate row sums (col i = l31)
        float pv[16];
#pragma unroll
        for (int r = 0; r < 16; r++) {
            float p = exp2f(st0[r] + st1[r]);
            pv[r] = p;
            lsum += p;
        }

        // ---- pack: pk[g] = rows 4g..4g+3 (j_local = r + 8g + 4*hbp_src)
        unsigned pkx[4], pky[4];
#pragma unroll
        for (int g = 0; g < 4; g++) {
            pkx[g] = packbf(pv[4 * g], pv[4 * g + 1]);
            pky[g] = packbf(pv[4 * g + 2], pv[4 * g + 3]);
        }

        // ---- PV over this wave's 32 j: 2 k-windows (jb), xor32 exchange
#pragma unroll
        for (int jb = 0; jb < 2; jb++) {
            // own g = 2jb + hbp ; send g = 2jb + 1 - hbp (what partner needs)
            unsigned ox = hbp ? pkx[2 * jb + 1] : pkx[2 * jb];
            unsigned oy = hbp ? pky[2 * jb + 1] : pky[2 * jb];
            unsigned sx = hbp ? pkx[2 * jb] : pkx[2 * jb + 1];
            unsigned sy = hbp ? pky[2 * jb] : pky[2 * jb + 1];
            unsigned rx = (unsigned)__shfl_xor((int)sx, 32);
            unsigned ry = (unsigned)__shfl_xor((int)sy, 32);
            union { unsigned u[4]; bf16x8 v; } pa;
            pa.u[0] = hbp ? rx : ox;   // e 0..1
            pa.u[1] = hbp ? ry : oy;   // e 2..3
            pa.u[2] = hbp ? ox : rx;   // e 4..5
            pa.u[3] = hbp ? oy : ry;   // e 6..7
#pragma unroll
            for (int cs = 0; cs < 4; cs++) {
                bf16x8 bv = *(const bf16x8*)&vlds[cur][(cs * 4 + jh * 2 + jb) * 512 + lane * 8];
                oacc[cs] = __builtin_amdgcn_mfma_f32_32x32x16_bf16(pa.v, bv, oacc[cs], 0, 0, 0);
            }
        }
    }

    // ---- reduce row sums across hb halves
    lsum += __shfl_xor(lsum, 32);

    // ---- merge j-halves (waves w and w^2) through LDS
    __syncthreads();
    float* mf = (float*)vlds;   // 8192 floats
    float* kf = (float*)klds;
    if (jh == 1) {
#pragma unroll
        for (int cs = 0; cs < 4; cs++)
#pragma unroll
            for (int r = 0; r < 16; r++)
                mf[qh * 4096 + (cs * 16 + r) * 64 + lane] = oacc[cs][r];
        kf[qh * 64 + lane] = lsum;
    }
    __syncthreads();
    if (jh == 0) {
#pragma unroll
        for (int cs = 0; cs < 4; cs++)
#pragma unroll
            for (int r = 0; r < 16; r++)
                oacc[cs][r] += mf[qh * 4096 + (cs * 16 + r) * 64 + lane];
        lsum += kf[qh * 64 + lane];
        float inv = 1.0f / lsum;
        float ir[16];
#pragma unroll
        for (int r = 0; r < 16; r++) {
            int row = (r & 3) + 8 * (r >> 2) + 4 * hbp;
            ir[r] = __shfl(inv, row);   // lane 'row' holds inv for i-local=row
        }
#pragma unroll
        for (int cs = 0; cs < 4; cs++)
#pragma unroll
            for (int r = 0; r < 16; r++) {
                int row = (r & 3) + 8 * (r >> 2) + 4 * hbp;
                int c = h * 128 + cs * 32 + l31;
                ot[((size_t)b * 1024 + i0 + row) * 256 + c] = f2bf(oacc[cs][r] * ir[r]);
            }
    }
}

// ------------------------------------------------------ proj + residual
__global__ __launch_bounds__(256) void proj_gemm(const unsigned short* __restrict__ wpb,
                                                 const unsigned short* __restrict__ ot,
                                                 const float* __restrict__ x,
                                                 float* __restrict__ out) {
    int b = blockIdx.z;
    int my = blockIdx.y;   // 0..1
    int nx = blockIdx.x;   // 0..15
    int tid = threadIdx.x;
    int w = tid >> 6, lane = tid & 63, quad = lane >> 4, c4 = lane & 15;
    int wm = (w >> 1) * 64, wn = (w & 1) * 32;
    int mbase = my * 128 + wm;
    int nbase = nx * 64 + wn;
    const unsigned short* ob = ot + (size_t)b * 1024 * 256;

    f32x4 acc[4][2] = {};
#pragma unroll
    for (int k = 0; k < 256; k += 32) {
        bf16x8 af[4], bfr[2];
#pragma unroll
        for (int i = 0; i < 4; i++)
            af[i] = *(const bf16x8*)(wpb + (mbase + i * 16 + c4) * 256 + k + quad * 8);
#pragma unroll
        for (int i = 0; i < 2; i++)
            bfr[i] = *(const bf16x8*)(ob + (size_t)(nbase + i * 16 + c4) * 256 + k + quad * 8);
#pragma unroll
        for (int mi = 0; mi < 4; mi++)
#pragma unroll
            for (int ni = 0; ni < 2; ni++)
                acc[mi][ni] = __builtin_amdgcn_mfma_f32_16x16x32_bf16(
                    af[mi], bfr[ni], acc[mi][ni], 0, 0, 0);
    }
#pragma unroll
    for (int mi = 0; mi < 4; mi++)
#pragma unroll
        for (int ni = 0; ni < 2; ni++)
#pragma unroll
            for (int r = 0; r < 4; r++) {
                int o = mbase + mi * 16 + quad * 4 + r;
                int i = nbase + ni * 16 + c4;
                size_t idx = ((size_t)b * 256 + o) * 1024 + i;
                out[idx] = acc[mi][ni][r] + x[idx];
            }
}

// ---------------------------------------------------------------------------
extern "C" void kernel_launch(void* const* d_in, const int* in_sizes, int n_in,
                              void* d_out, int out_size, void* d_ws, size_t ws_size,
                              hipStream_t stream) {
    const float* x   = (const float*)d_in[0];
    const float* gnw = (const float*)d_in[1];
    const float* gnb = (const float*)d_in[2];
    const float* wq  = (const float*)d_in[3];
    const float* wk  = (const float*)d_in[4];
    const float* wv  = (const float*)d_in[5];
    const float* wp  = (const float*)d_in[6];
    float* out = (float*)d_out;

    char* ws = (char*)d_ws;
    float* acc = (float*)ws;                                        //   4 KiB
    unsigned short* wqb = (unsigned short*)(ws + 4096);             // 128 KiB each
    unsigned short* wkb = (unsigned short*)(ws + 4096 + 131072);
    unsigned short* wvb = (unsigned short*)(ws + 4096 + 2 * 131072);
    unsigned short* wpb = (unsigned short*)(ws + 4096 + 3 * 131072);
    size_t base = 4096 + 4 * 131072;
    const size_t SZ = (size_t)16 * 1024 * 256 * 2;  // 8 MiB each
    unsigned short* qt = (unsigned short*)(ws + base);
    unsigned short* kt = (unsigned short*)(ws + base + SZ);
    unsigned short* vv = (unsigned short*)(ws + base + 2 * SZ);
    unsigned short* ot = (unsigned short*)(ws + base + 3 * SZ);

    prep<<<768, 256, 0, stream>>>(wq, wk, wv, wp, wqb, wkb, wvb, wpb, x, acc);
    qkv_fused<<<dim3(16, 2, 16), 256, 0, stream>>>(x, acc, gnw, gnb,
                                                   wqb, wkb, wvb, qt, kt, vv);
    attn_kernel<<<512, 256, 0, stream>>>(qt, kt, vv, ot);
    proj_gemm<<<dim3(16, 2, 16), 256, 0, stream>>>(wpb, ot, x, out);
}